// Round 3
// baseline (283.159 us; speedup 1.0000x reference)
//
#include <hip/hip_runtime.h>

// B=32, C=3, H=W=512, window 11, sigma 1.5, VALID conv -> 502x502
#define H 512
#define W 512
#define OUT_Wc 502
#define OUT_Hc 502
#define C1c 1.0e-4f   // (0.01*1)^2
#define C2c 9.0e-4f   // (0.03*1)^2

#define TH 56             // output rows per block (9 y-tiles cover 502..504)
#define NR 66             // TH+10 input rows, multiple of 11 (phase-aligned)
#define HALO 10
#define RSTRIDE 74        // 64 main cols + 10 halo cols per wave

// Barrier-free row-streaming SSIM:
//  - each WAVE owns 64 output columns and a private LDS ring (74 cols) ->
//    no __syncthreads anywhere; intra-wave ds_write->ds_read is in-order,
//    __builtin_amdgcn_wave_barrier() pins compiler ordering.
//  - per input row: stage (x1,x2) pairs, horizontal 11-tap conv of 5
//    quantities (products on the fly), scatter into 11 phase-unrolled
//    vertical accumulators (registers). Slot p re-inits by MUL at row r===p
//    (mod 11) -- exactly its output window start, no explicit resets.
//  - uniform (SALU) row base pointers + constant lane offsets -> near-zero
//    VALU address math; 1-row register prefetch hides global latency.
__global__ __launch_bounds__(256, 5) void ssim_kernel(const float* __restrict__ img1,
                                                      const float* __restrict__ img2,
                                                      float* __restrict__ out) {
    __shared__ float2 ring[4][2][RSTRIDE];   // [wave][slot][col]

    // normalized Gaussian, sigma=1.5, ws=11 (matches reference to ~1e-7)
    constexpr float GW[11] = {0.00102838f, 0.00759876f, 0.03600078f, 0.10936067f,
                              0.21300555f, 0.26601174f, 0.21300555f, 0.10936067f,
                              0.03600078f, 0.00759876f, 0.00102838f};

    const int tid  = threadIdx.x;
    const int wv   = tid >> 6;
    const int lane = tid & 63;

    const int plane = blockIdx.z;                 // b*3 + c
    const size_t pbase = (size_t)plane * (H * W);
    const float* __restrict__ p1 = img1 + pbase;
    const float* __restrict__ p2 = img2 + pbase;

    const int Y0    = blockIdx.y * TH;
    const int wcol0 = (blockIdx.x * 4 + wv) * 64; // wave's first column
    const int gx    = wcol0 + lane;               // 0..511
    const int hx    = min(wcol0 + 64 + lane, W - 1);  // halo col (lane<10), clamped

    float2 (* __restrict__ wring)[RSTRIDE] = ring[wv];

    float acc0[11], acc1[11], acc2[11], acc3[11], acc4[11];
#pragma unroll
    for (int i = 0; i < 11; ++i) { acc0[i]=0.f; acc1[i]=0.f; acc2[i]=0.f; acc3[i]=0.f; acc4[i]=0.f; }

    const bool colok = (gx < OUT_Wc);
    float lsum = 0.f;

    // prime prefetch (row 0; Y0 <= 448 so always in range)
    {
        const float* r1 = p1 + (size_t)Y0 * W;
        const float* r2 = p2 + (size_t)Y0 * W;
        // declared below
    }
    const float* r1p = p1 + (size_t)Y0 * W;
    const float* r2p = p2 + (size_t)Y0 * W;
    float a1 = r1p[gx], a2 = r2p[gx];
    float b1 = 0.f, b2 = 0.f;
    if (lane < HALO) { b1 = r1p[hx]; b2 = r2p[hx]; }

#pragma unroll 1
    for (int rb = 0; rb < NR; rb += 11) {
#pragma unroll
        for (int p = 0; p < 11; ++p) {
            const int r = rb + p;
            const int slot = r & 1;

            // stage current row into this wave's ring
            wring[slot][lane] = make_float2(a1, a2);

            // next-row base (uniform -> SALU); clamp keeps loads in-bounds,
            // clamped rows only feed discarded outputs
            const int gy = min(Y0 + r + 1, H - 1);
            const float* __restrict__ n1 = p1 + (size_t)gy * W;
            const float* __restrict__ n2 = p2 + (size_t)gy * W;

            if (lane < HALO) {
                wring[slot][64 + lane] = make_float2(b1, b2);
                b1 = n1[hx]; b2 = n2[hx];
            }
            a1 = n1[gx]; a2 = n2[gx];

            __builtin_amdgcn_wave_barrier();   // pin ds_writes before ds_reads

            // horizontal 11-tap conv of 5 quantities (products on the fly)
            float h0, h1, h2, h3, h4;
#pragma unroll
            for (int t = 0; t < 11; ++t) {
                const float2 v = wring[slot][lane + t];
                const float w = GW[t];
                if (t == 0) {
                    h0 = w * v.x;         h1 = w * v.y;
                    h2 = w * (v.x * v.x); h3 = w * (v.y * v.y);
                    h4 = w * (v.x * v.y);
                } else {
                    h0 = fmaf(w, v.x,       h0);
                    h1 = fmaf(w, v.y,       h1);
                    h2 = fmaf(w, v.x * v.x, h2);
                    h3 = fmaf(w, v.y * v.y, h3);
                    h4 = fmaf(w, v.x * v.y, h4);
                }
            }

            // vertical scatter: slot a gets weight GW[(p-a) mod 11];
            // slot a==p starts a fresh output window -> init by mul
#pragma unroll
            for (int a = 0; a < 11; ++a) {
                const float w = GW[(p - a + 11) % 11];   // compile-time
                if (a == p) {
                    acc0[a] = w * h0; acc1[a] = w * h1; acc2[a] = w * h2;
                    acc3[a] = w * h3; acc4[a] = w * h4;
                } else {
                    acc0[a] = fmaf(w, h0, acc0[a]);
                    acc1[a] = fmaf(w, h1, acc1[a]);
                    acc2[a] = fmaf(w, h2, acc2[a]);
                    acc3[a] = fmaf(w, h3, acc3[a]);
                    acc4[a] = fmaf(w, h4, acc4[a]);
                }
            }

            // output row oy = Y0 + r - 10 completes in slot e = (p+1)%11
            const int e = (p + 1) % 11;
            const int oy = Y0 + r - 10;
            if (r >= 10 && oy < OUT_Hc) {          // uniform branch
                const float m1 = acc0[e], m2 = acc1[e];
                const float m12 = m1 * m2;
                const float sig1  = fmaf(-m1, m1, acc2[e]);
                const float sig2  = fmaf(-m2, m2, acc3[e]);
                const float sig12 = fmaf(-m1, m2, acc4[e]);
                const float num_a = fmaf(2.f, m12,   C1c);
                const float num_b = fmaf(2.f, sig12, C2c);
                const float den_a = fmaf(m1, m1, fmaf(m2, m2, C1c));
                const float den_b = (sig1 + sig2) + C2c;
                const float v = (num_a * num_b) * __builtin_amdgcn_rcpf(den_a * den_b);
                lsum += colok ? v : 0.f;
            }
        }
    }

    // per-wave reduce + one atomic per wave
#pragma unroll
    for (int off = 32; off > 0; off >>= 1) lsum += __shfl_down(lsum, off, 64);
    if (lane == 0) {
        const float inv_count = 1.0f / (3.0f * (float)OUT_Hc * (float)OUT_Wc);
        atomicAdd(&out[plane / 3], lsum * inv_count);
    }
}

__global__ void zero_out(float* out, int n) {
    int i = threadIdx.x + blockIdx.x * blockDim.x;
    if (i < n) out[i] = 0.f;
}

extern "C" void kernel_launch(void* const* d_in, const int* in_sizes, int n_in,
                              void* d_out, int out_size, void* d_ws, size_t ws_size,
                              hipStream_t stream) {
    const float* img1 = (const float*)d_in[0];
    const float* img2 = (const float*)d_in[1];
    float* out = (float*)d_out;

    zero_out<<<1, 64, 0, stream>>>(out, out_size);

    const int nplanes = in_sizes[0] / (H * W);     // 96
    dim3 grid(2,                                   // 2 * 4 waves * 64 cols = 512
              (OUT_Hc + TH - 1) / TH,              // 9
              nplanes);
    ssim_kernel<<<grid, 256, 0, stream>>>(img1, img2, out);
}